// Round 1
// baseline (6107.790 us; speedup 1.0000x reference)
//
#include <hip/hip_runtime.h>
#include <math.h>

#define TIN   32
#define THID  32
#define TOUT  32
#define TEDGE 8
#define TK1   73   // 2*IN + EDGE + 1

__device__ __forceinline__ float silu_f(float x) {
    return x * (1.0f / (1.0f + __expf(-x)));
}

__global__ __launch_bounds__(256) void egnn_edge(
    const float* __restrict__ node_feat,
    const float* __restrict__ coord,
    const float* __restrict__ edge_feat,
    const int*   __restrict__ src,
    const int*   __restrict__ dst,
    const float* __restrict__ We1,
    const float* __restrict__ be1,
    const float* __restrict__ We2,
    const float* __restrict__ be2,
    const float* __restrict__ Wc1,
    const float* __restrict__ bc1,
    const float* __restrict__ Wc2,
    float* __restrict__ h_acc,   // [N][32]
    float* __restrict__ x_acc,   // [N][3]
    float* __restrict__ deg,     // [N]
    int E)
{
    int e = blockIdx.x * 256 + threadIdx.x;
    if (e >= E) return;

    int s = src[e];
    int d = dst[e];

    // coordinate difference + radial
    float dx0 = coord[3*(size_t)s+0] - coord[3*(size_t)d+0];
    float dx1 = coord[3*(size_t)s+1] - coord[3*(size_t)d+1];
    float dx2 = coord[3*(size_t)s+2] - coord[3*(size_t)d+2];
    float radial = dx0*dx0 + dx1*dx1 + dx2*dx2;
    float invn = 1.0f / (sqrtf(radial) + 1e-30f);
    dx0 *= invn; dx1 *= invn; dx2 *= invn;

    // build f[73] = [h_src(32), h_dst(32), radial(1), edge_feat(8)]
    float f[TK1];
    {
        const float4* p = reinterpret_cast<const float4*>(node_feat + (size_t)s * TIN);
        #pragma unroll
        for (int i = 0; i < TIN/4; ++i) {
            float4 v = p[i];
            f[4*i+0] = v.x; f[4*i+1] = v.y; f[4*i+2] = v.z; f[4*i+3] = v.w;
        }
    }
    {
        const float4* p = reinterpret_cast<const float4*>(node_feat + (size_t)d * TIN);
        #pragma unroll
        for (int i = 0; i < TIN/4; ++i) {
            float4 v = p[i];
            f[TIN+4*i+0] = v.x; f[TIN+4*i+1] = v.y; f[TIN+4*i+2] = v.z; f[TIN+4*i+3] = v.w;
        }
    }
    f[64] = radial;
    {
        const float4* p = reinterpret_cast<const float4*>(edge_feat + (size_t)e * TEDGE);
        #pragma unroll
        for (int i = 0; i < TEDGE/4; ++i) {
            float4 v = p[i];
            f[65+4*i+0] = v.x; f[65+4*i+1] = v.y; f[65+4*i+2] = v.z; f[65+4*i+3] = v.w;
        }
    }

    // edge MLP layer 1: [73] @ [73,32] + be1, silu
    float a1[THID];
    #pragma unroll
    for (int j = 0; j < THID; ++j) a1[j] = be1[j];
    #pragma unroll
    for (int k = 0; k < TK1; ++k) {
        float fk = f[k];
        #pragma unroll
        for (int j = 0; j < THID; ++j)
            a1[j] = fmaf(fk, We1[k*THID + j], a1[j]);
    }
    #pragma unroll
    for (int j = 0; j < THID; ++j) a1[j] = silu_f(a1[j]);

    // edge MLP layer 2: [32] @ [32,32] + be2, silu  -> msg_h
    float msg[THID];
    #pragma unroll
    for (int j = 0; j < THID; ++j) msg[j] = be2[j];
    #pragma unroll
    for (int k = 0; k < THID; ++k) {
        float fk = a1[k];
        #pragma unroll
        for (int j = 0; j < THID; ++j)
            msg[j] = fmaf(fk, We2[k*THID + j], msg[j]);
    }
    #pragma unroll
    for (int j = 0; j < THID; ++j) msg[j] = silu_f(msg[j]);

    // coord gate: silu(msg @ Wc1 + bc1) @ Wc2
    float c1[THID];
    #pragma unroll
    for (int j = 0; j < THID; ++j) c1[j] = bc1[j];
    #pragma unroll
    for (int k = 0; k < THID; ++k) {
        float fk = msg[k];
        #pragma unroll
        for (int j = 0; j < THID; ++j)
            c1[j] = fmaf(fk, Wc1[k*THID + j], c1[j]);
    }
    float gate = 0.0f;
    #pragma unroll
    for (int j = 0; j < THID; ++j) gate = fmaf(silu_f(c1[j]), Wc2[j], gate);

    // scatter (atomic) to dst
    float* ha = h_acc + (size_t)d * THID;
    #pragma unroll
    for (int j = 0; j < THID; ++j) atomicAdd(ha + j, msg[j]);
    atomicAdd(x_acc + (size_t)d*3 + 0, gate * dx0);
    atomicAdd(x_acc + (size_t)d*3 + 1, gate * dx1);
    atomicAdd(x_acc + (size_t)d*3 + 2, gate * dx2);
    atomicAdd(deg + d, 1.0f);
}

__global__ __launch_bounds__(256) void egnn_node(
    const float* __restrict__ node_feat,
    const float* __restrict__ coord,
    const float* __restrict__ Wn1,
    const float* __restrict__ bn1,
    const float* __restrict__ Wn2,
    const float* __restrict__ bn2,
    const float* __restrict__ h_acc,
    const float* __restrict__ x_acc,
    const float* __restrict__ deg,
    float* __restrict__ out_h,   // [N][32]
    float* __restrict__ out_x,   // [N][3]
    int N)
{
    int n = blockIdx.x * 256 + threadIdx.x;
    if (n >= N) return;

    // f2[64] = [node_feat(32), h_neigh(32)]
    float f2[2*TIN];
    {
        const float4* p = reinterpret_cast<const float4*>(node_feat + (size_t)n * TIN);
        #pragma unroll
        for (int i = 0; i < TIN/4; ++i) {
            float4 v = p[i];
            f2[4*i+0] = v.x; f2[4*i+1] = v.y; f2[4*i+2] = v.z; f2[4*i+3] = v.w;
        }
    }
    {
        const float4* p = reinterpret_cast<const float4*>(h_acc + (size_t)n * THID);
        #pragma unroll
        for (int i = 0; i < THID/4; ++i) {
            float4 v = p[i];
            f2[TIN+4*i+0] = v.x; f2[TIN+4*i+1] = v.y; f2[TIN+4*i+2] = v.z; f2[TIN+4*i+3] = v.w;
        }
    }

    float a[THID];
    #pragma unroll
    for (int j = 0; j < THID; ++j) a[j] = bn1[j];
    #pragma unroll
    for (int k = 0; k < 2*TIN; ++k) {
        float fk = f2[k];
        #pragma unroll
        for (int j = 0; j < THID; ++j)
            a[j] = fmaf(fk, Wn1[k*THID + j], a[j]);
    }
    #pragma unroll
    for (int j = 0; j < THID; ++j) a[j] = silu_f(a[j]);

    float h[TOUT];
    #pragma unroll
    for (int j = 0; j < TOUT; ++j) h[j] = bn2[j];
    #pragma unroll
    for (int k = 0; k < THID; ++k) {
        float fk = a[k];
        #pragma unroll
        for (int j = 0; j < TOUT; ++j)
            h[j] = fmaf(fk, Wn2[k*TOUT + j], h[j]);
    }

    float4* po = reinterpret_cast<float4*>(out_h + (size_t)n * TOUT);
    #pragma unroll
    for (int i = 0; i < TOUT/4; ++i) {
        float4 v; v.x = h[4*i+0]; v.y = h[4*i+1]; v.z = h[4*i+2]; v.w = h[4*i+3];
        po[i] = v;
    }

    float dg = fmaxf(deg[n], 1.0f);
    float inv = 1.0f / dg;
    out_x[(size_t)n*3+0] = coord[(size_t)n*3+0] + x_acc[(size_t)n*3+0] * inv;
    out_x[(size_t)n*3+1] = coord[(size_t)n*3+1] + x_acc[(size_t)n*3+1] * inv;
    out_x[(size_t)n*3+2] = coord[(size_t)n*3+2] + x_acc[(size_t)n*3+2] * inv;
}

extern "C" void kernel_launch(void* const* d_in, const int* in_sizes, int n_in,
                              void* d_out, int out_size, void* d_ws, size_t ws_size,
                              hipStream_t stream) {
    const float* node_feat = (const float*)d_in[0];
    const float* coord     = (const float*)d_in[1];
    const float* edge_feat = (const float*)d_in[2];
    const int*   src       = (const int*)d_in[3];
    const int*   dst       = (const int*)d_in[4];
    const float* We1 = (const float*)d_in[5];
    const float* be1 = (const float*)d_in[6];
    const float* We2 = (const float*)d_in[7];
    const float* be2 = (const float*)d_in[8];
    const float* Wn1 = (const float*)d_in[9];
    const float* bn1 = (const float*)d_in[10];
    const float* Wn2 = (const float*)d_in[11];
    const float* bn2 = (const float*)d_in[12];
    const float* Wc1 = (const float*)d_in[13];
    const float* bc1 = (const float*)d_in[14];
    const float* Wc2 = (const float*)d_in[15];

    int N = in_sizes[0] / TIN;
    int E = in_sizes[3];

    float* h_acc = (float*)d_ws;                 // N*32
    float* x_acc = h_acc + (size_t)N * THID;     // N*3
    float* degv  = x_acc + (size_t)N * 3;        // N
    size_t zero_bytes = sizeof(float) * (size_t)N * (THID + 3 + 1);
    hipMemsetAsync(d_ws, 0, zero_bytes, stream);

    float* out_h = (float*)d_out;
    float* out_x = out_h + (size_t)N * TOUT;

    egnn_edge<<<(E + 255) / 256, 256, 0, stream>>>(
        node_feat, coord, edge_feat, src, dst,
        We1, be1, We2, be2, Wc1, bc1, Wc2,
        h_acc, x_acc, degv, E);

    egnn_node<<<(N + 255) / 256, 256, 0, stream>>>(
        node_feat, coord, Wn1, bn1, Wn2, bn2,
        h_acc, x_acc, degv, out_h, out_x, N);
}

// Round 2
// 1045.422 us; speedup vs baseline: 5.8424x; 5.8424x over previous
//
#include <hip/hip_runtime.h>
#include <math.h>

#define TIN   32
#define THID  32
#define TOUT  32
#define TEDGE 8
#define TK1   73   // 2*IN + EDGE + 1
#define ROWU  20   // uints per sorted message row: 16 (32 bf16 h) + 3 (f32 x) + 1 pad

__device__ __forceinline__ float silu_f(float x) {
    return x * (1.0f / (1.0f + __expf(-x)));
}

__device__ __forceinline__ unsigned int bf16_rne(float x) {
    unsigned int u = __float_as_uint(x);
    return (u + 0x7FFFu + ((u >> 16) & 1u)) >> 16;
}

// ---------------- phase 1: histogram of dst ----------------
__global__ __launch_bounds__(256) void hist_kernel(
    const int* __restrict__ dst, int* __restrict__ hist, int E)
{
    int e = blockIdx.x * 256 + threadIdx.x;
    if (e < E) atomicAdd(&hist[dst[e]], 1);
}

// ---------------- phase 2: exclusive scan (single block) ----------------
__global__ __launch_bounds__(1024) void scan_hist(
    const int* __restrict__ hist, int* __restrict__ base, int N)
{
    __shared__ int partial[1024];
    int t = threadIdx.x;
    int chunk = (N + 1023) / 1024;
    int begin = t * chunk;
    int end   = begin + chunk; if (end > N) end = N;
    int s = 0;
    for (int i = begin; i < end; ++i) s += hist[i];
    partial[t] = s;
    __syncthreads();
    for (int off = 1; off < 1024; off <<= 1) {
        int v = (t >= off) ? partial[t - off] : 0;
        __syncthreads();
        partial[t] += v;
        __syncthreads();
    }
    int run = (t == 0) ? 0 : partial[t - 1];
    for (int i = begin; i < end; ++i) { base[i] = run; run += hist[i]; }
    if (t == 1023) base[N] = partial[1023];
}

// ---------------- phase 3: edge MLP, write dst-sorted packed messages ----------------
__global__ __launch_bounds__(256) void egnn_edge_sorted(
    const float* __restrict__ node_feat,
    const float* __restrict__ coord,
    const float* __restrict__ edge_feat,
    const int*   __restrict__ src,
    const int*   __restrict__ dst,
    const float* __restrict__ We1,
    const float* __restrict__ be1,
    const float* __restrict__ We2,
    const float* __restrict__ be2,
    const float* __restrict__ Wc1,
    const float* __restrict__ bc1,
    const float* __restrict__ Wc2,
    int* __restrict__ cursor,
    unsigned int* __restrict__ msg_sorted,   // [E][ROWU]
    int E)
{
    int e = blockIdx.x * 256 + threadIdx.x;
    if (e >= E) return;

    int s = src[e];
    int d = dst[e];

    float dx0 = coord[3*(size_t)s+0] - coord[3*(size_t)d+0];
    float dx1 = coord[3*(size_t)s+1] - coord[3*(size_t)d+1];
    float dx2 = coord[3*(size_t)s+2] - coord[3*(size_t)d+2];
    float radial = dx0*dx0 + dx1*dx1 + dx2*dx2;
    float invn = 1.0f / (sqrtf(radial) + 1e-30f);
    dx0 *= invn; dx1 *= invn; dx2 *= invn;

    float f[TK1];
    {
        const float4* p = reinterpret_cast<const float4*>(node_feat + (size_t)s * TIN);
        #pragma unroll
        for (int i = 0; i < TIN/4; ++i) {
            float4 v = p[i];
            f[4*i+0] = v.x; f[4*i+1] = v.y; f[4*i+2] = v.z; f[4*i+3] = v.w;
        }
    }
    {
        const float4* p = reinterpret_cast<const float4*>(node_feat + (size_t)d * TIN);
        #pragma unroll
        for (int i = 0; i < TIN/4; ++i) {
            float4 v = p[i];
            f[TIN+4*i+0] = v.x; f[TIN+4*i+1] = v.y; f[TIN+4*i+2] = v.z; f[TIN+4*i+3] = v.w;
        }
    }
    f[64] = radial;
    {
        const float4* p = reinterpret_cast<const float4*>(edge_feat + (size_t)e * TEDGE);
        #pragma unroll
        for (int i = 0; i < TEDGE/4; ++i) {
            float4 v = p[i];
            f[65+4*i+0] = v.x; f[65+4*i+1] = v.y; f[65+4*i+2] = v.z; f[65+4*i+3] = v.w;
        }
    }

    float a1[THID];
    #pragma unroll
    for (int j = 0; j < THID; ++j) a1[j] = be1[j];
    #pragma unroll
    for (int k = 0; k < TK1; ++k) {
        float fk = f[k];
        #pragma unroll
        for (int j = 0; j < THID; ++j)
            a1[j] = fmaf(fk, We1[k*THID + j], a1[j]);
    }
    #pragma unroll
    for (int j = 0; j < THID; ++j) a1[j] = silu_f(a1[j]);

    float msg[THID];
    #pragma unroll
    for (int j = 0; j < THID; ++j) msg[j] = be2[j];
    #pragma unroll
    for (int k = 0; k < THID; ++k) {
        float fk = a1[k];
        #pragma unroll
        for (int j = 0; j < THID; ++j)
            msg[j] = fmaf(fk, We2[k*THID + j], msg[j]);
    }
    #pragma unroll
    for (int j = 0; j < THID; ++j) msg[j] = silu_f(msg[j]);

    float c1[THID];
    #pragma unroll
    for (int j = 0; j < THID; ++j) c1[j] = bc1[j];
    #pragma unroll
    for (int k = 0; k < THID; ++k) {
        float fk = msg[k];
        #pragma unroll
        for (int j = 0; j < THID; ++j)
            c1[j] = fmaf(fk, Wc1[k*THID + j], c1[j]);
    }
    float gate = 0.0f;
    #pragma unroll
    for (int j = 0; j < THID; ++j) gate = fmaf(silu_f(c1[j]), Wc2[j], gate);

    // pack: 32 bf16 h + 3 f32 x + pad
    unsigned int row[ROWU];
    #pragma unroll
    for (int j = 0; j < 16; ++j)
        row[j] = bf16_rne(msg[2*j]) | (bf16_rne(msg[2*j+1]) << 16);
    row[16] = __float_as_uint(gate * dx0);
    row[17] = __float_as_uint(gate * dx1);
    row[18] = __float_as_uint(gate * dx2);
    row[19] = 0u;

    int pos = atomicAdd(&cursor[d], 1);
    uint4* out = reinterpret_cast<uint4*>(msg_sorted + (size_t)pos * ROWU);
    #pragma unroll
    for (int i = 0; i < ROWU/4; ++i) {
        uint4 v; v.x = row[4*i+0]; v.y = row[4*i+1]; v.z = row[4*i+2]; v.w = row[4*i+3];
        out[i] = v;
    }
}

// ---------------- phase 4: segment-sum the sorted messages ----------------
__global__ __launch_bounds__(256) void aggregate_kernel(
    const unsigned int* __restrict__ msg_sorted,
    const int* __restrict__ base,
    float* __restrict__ h_acc,   // [N][32]
    float* __restrict__ x_acc,   // [N][3]
    float* __restrict__ deg,     // [N]
    int N)
{
    int g    = (blockIdx.x * 256 + threadIdx.x) >> 5;  // node id
    int lane = threadIdx.x & 31;
    if (g >= N) return;

    int s = base[g], e = base[g+1];
    bool isH = lane < 16;
    bool isX = (lane >= 16) && (lane < 19);
    float sum0 = 0.0f, sum1 = 0.0f;
    for (int j = s; j < e; ++j) {
        unsigned int v = (lane < 19) ? msg_sorted[(size_t)j * ROWU + lane] : 0u;
        if (isH) {
            sum0 += __uint_as_float((v & 0xFFFFu) << 16);
            sum1 += __uint_as_float(v & 0xFFFF0000u);
        } else if (isX) {
            sum0 += __uint_as_float(v);
        }
    }
    if (isH) {
        float2* p = reinterpret_cast<float2*>(h_acc + (size_t)g * THID + 2 * lane);
        float2 v; v.x = sum0; v.y = sum1;
        *p = v;
    } else if (isX) {
        x_acc[(size_t)g * 3 + (lane - 16)] = sum0;
    } else if (lane == 19) {
        deg[g] = (float)(e - s);
    }
}

// ---------------- fallback: original atomic edge kernel ----------------
__global__ __launch_bounds__(256) void egnn_edge_atomic(
    const float* __restrict__ node_feat,
    const float* __restrict__ coord,
    const float* __restrict__ edge_feat,
    const int*   __restrict__ src,
    const int*   __restrict__ dst,
    const float* __restrict__ We1,
    const float* __restrict__ be1,
    const float* __restrict__ We2,
    const float* __restrict__ be2,
    const float* __restrict__ Wc1,
    const float* __restrict__ bc1,
    const float* __restrict__ Wc2,
    float* __restrict__ h_acc,
    float* __restrict__ x_acc,
    float* __restrict__ deg,
    int E)
{
    int e = blockIdx.x * 256 + threadIdx.x;
    if (e >= E) return;
    int s = src[e];
    int d = dst[e];
    float dx0 = coord[3*(size_t)s+0] - coord[3*(size_t)d+0];
    float dx1 = coord[3*(size_t)s+1] - coord[3*(size_t)d+1];
    float dx2 = coord[3*(size_t)s+2] - coord[3*(size_t)d+2];
    float radial = dx0*dx0 + dx1*dx1 + dx2*dx2;
    float invn = 1.0f / (sqrtf(radial) + 1e-30f);
    dx0 *= invn; dx1 *= invn; dx2 *= invn;
    float f[TK1];
    {
        const float4* p = reinterpret_cast<const float4*>(node_feat + (size_t)s * TIN);
        #pragma unroll
        for (int i = 0; i < TIN/4; ++i) {
            float4 v = p[i];
            f[4*i+0]=v.x; f[4*i+1]=v.y; f[4*i+2]=v.z; f[4*i+3]=v.w;
        }
    }
    {
        const float4* p = reinterpret_cast<const float4*>(node_feat + (size_t)d * TIN);
        #pragma unroll
        for (int i = 0; i < TIN/4; ++i) {
            float4 v = p[i];
            f[TIN+4*i+0]=v.x; f[TIN+4*i+1]=v.y; f[TIN+4*i+2]=v.z; f[TIN+4*i+3]=v.w;
        }
    }
    f[64] = radial;
    {
        const float4* p = reinterpret_cast<const float4*>(edge_feat + (size_t)e * TEDGE);
        #pragma unroll
        for (int i = 0; i < TEDGE/4; ++i) {
            float4 v = p[i];
            f[65+4*i+0]=v.x; f[65+4*i+1]=v.y; f[65+4*i+2]=v.z; f[65+4*i+3]=v.w;
        }
    }
    float a1[THID];
    #pragma unroll
    for (int j = 0; j < THID; ++j) a1[j] = be1[j];
    #pragma unroll
    for (int k = 0; k < TK1; ++k) {
        float fk = f[k];
        #pragma unroll
        for (int j = 0; j < THID; ++j) a1[j] = fmaf(fk, We1[k*THID + j], a1[j]);
    }
    #pragma unroll
    for (int j = 0; j < THID; ++j) a1[j] = silu_f(a1[j]);
    float msg[THID];
    #pragma unroll
    for (int j = 0; j < THID; ++j) msg[j] = be2[j];
    #pragma unroll
    for (int k = 0; k < THID; ++k) {
        float fk = a1[k];
        #pragma unroll
        for (int j = 0; j < THID; ++j) msg[j] = fmaf(fk, We2[k*THID + j], msg[j]);
    }
    #pragma unroll
    for (int j = 0; j < THID; ++j) msg[j] = silu_f(msg[j]);
    float c1[THID];
    #pragma unroll
    for (int j = 0; j < THID; ++j) c1[j] = bc1[j];
    #pragma unroll
    for (int k = 0; k < THID; ++k) {
        float fk = msg[k];
        #pragma unroll
        for (int j = 0; j < THID; ++j) c1[j] = fmaf(fk, Wc1[k*THID + j], c1[j]);
    }
    float gate = 0.0f;
    #pragma unroll
    for (int j = 0; j < THID; ++j) gate = fmaf(silu_f(c1[j]), Wc2[j], gate);
    float* ha = h_acc + (size_t)d * THID;
    #pragma unroll
    for (int j = 0; j < THID; ++j) atomicAdd(ha + j, msg[j]);
    atomicAdd(x_acc + (size_t)d*3 + 0, gate * dx0);
    atomicAdd(x_acc + (size_t)d*3 + 1, gate * dx1);
    atomicAdd(x_acc + (size_t)d*3 + 2, gate * dx2);
    atomicAdd(deg + d, 1.0f);
}

// ---------------- phase 5: node update ----------------
__global__ __launch_bounds__(256) void egnn_node(
    const float* __restrict__ node_feat,
    const float* __restrict__ coord,
    const float* __restrict__ Wn1,
    const float* __restrict__ bn1,
    const float* __restrict__ Wn2,
    const float* __restrict__ bn2,
    const float* __restrict__ h_acc,
    const float* __restrict__ x_acc,
    const float* __restrict__ deg,
    float* __restrict__ out_h,
    float* __restrict__ out_x,
    int N)
{
    int n = blockIdx.x * 256 + threadIdx.x;
    if (n >= N) return;

    float f2[2*TIN];
    {
        const float4* p = reinterpret_cast<const float4*>(node_feat + (size_t)n * TIN);
        #pragma unroll
        for (int i = 0; i < TIN/4; ++i) {
            float4 v = p[i];
            f2[4*i+0]=v.x; f2[4*i+1]=v.y; f2[4*i+2]=v.z; f2[4*i+3]=v.w;
        }
    }
    {
        const float4* p = reinterpret_cast<const float4*>(h_acc + (size_t)n * THID);
        #pragma unroll
        for (int i = 0; i < THID/4; ++i) {
            float4 v = p[i];
            f2[TIN+4*i+0]=v.x; f2[TIN+4*i+1]=v.y; f2[TIN+4*i+2]=v.z; f2[TIN+4*i+3]=v.w;
        }
    }

    float a[THID];
    #pragma unroll
    for (int j = 0; j < THID; ++j) a[j] = bn1[j];
    #pragma unroll
    for (int k = 0; k < 2*TIN; ++k) {
        float fk = f2[k];
        #pragma unroll
        for (int j = 0; j < THID; ++j) a[j] = fmaf(fk, Wn1[k*THID + j], a[j]);
    }
    #pragma unroll
    for (int j = 0; j < THID; ++j) a[j] = silu_f(a[j]);

    float h[TOUT];
    #pragma unroll
    for (int j = 0; j < TOUT; ++j) h[j] = bn2[j];
    #pragma unroll
    for (int k = 0; k < THID; ++k) {
        float fk = a[k];
        #pragma unroll
        for (int j = 0; j < TOUT; ++j) h[j] = fmaf(fk, Wn2[k*TOUT + j], h[j]);
    }

    float4* po = reinterpret_cast<float4*>(out_h + (size_t)n * TOUT);
    #pragma unroll
    for (int i = 0; i < TOUT/4; ++i) {
        float4 v; v.x=h[4*i+0]; v.y=h[4*i+1]; v.z=h[4*i+2]; v.w=h[4*i+3];
        po[i] = v;
    }

    float dg = fmaxf(deg[n], 1.0f);
    float inv = 1.0f / dg;
    out_x[(size_t)n*3+0] = coord[(size_t)n*3+0] + x_acc[(size_t)n*3+0] * inv;
    out_x[(size_t)n*3+1] = coord[(size_t)n*3+1] + x_acc[(size_t)n*3+1] * inv;
    out_x[(size_t)n*3+2] = coord[(size_t)n*3+2] + x_acc[(size_t)n*3+2] * inv;
}

extern "C" void kernel_launch(void* const* d_in, const int* in_sizes, int n_in,
                              void* d_out, int out_size, void* d_ws, size_t ws_size,
                              hipStream_t stream) {
    const float* node_feat = (const float*)d_in[0];
    const float* coord     = (const float*)d_in[1];
    const float* edge_feat = (const float*)d_in[2];
    const int*   src       = (const int*)d_in[3];
    const int*   dst       = (const int*)d_in[4];
    const float* We1 = (const float*)d_in[5];
    const float* be1 = (const float*)d_in[6];
    const float* We2 = (const float*)d_in[7];
    const float* be2 = (const float*)d_in[8];
    const float* Wn1 = (const float*)d_in[9];
    const float* bn1 = (const float*)d_in[10];
    const float* Wn2 = (const float*)d_in[11];
    const float* bn2 = (const float*)d_in[12];
    const float* Wc1 = (const float*)d_in[13];
    const float* bc1 = (const float*)d_in[14];
    const float* Wc2 = (const float*)d_in[15];

    int N = in_sizes[0] / TIN;
    int E = in_sizes[3];

    float* out_h = (float*)d_out;
    float* out_x = out_h + (size_t)N * TOUT;

    // workspace layout (sorted path): msg_sorted first for 16B alignment
    unsigned int* msg_sorted = (unsigned int*)d_ws;
    float* h_acc = (float*)((char*)d_ws + (size_t)E * ROWU * 4);
    float* x_acc = h_acc + (size_t)N * THID;
    float* degv  = x_acc + (size_t)N * 3;
    int*   hist  = (int*)(degv + N);
    int*   basep = hist + N;
    int*   cursor = basep + (N + 1);
    size_t need = (size_t)((char*)(cursor + N) - (char*)d_ws);

    if (need <= ws_size) {
        hipMemsetAsync(hist, 0, (size_t)N * 4, stream);
        hist_kernel<<<(E + 255) / 256, 256, 0, stream>>>(dst, hist, E);
        scan_hist<<<1, 1024, 0, stream>>>(hist, basep, N);
        hipMemcpyAsync(cursor, basep, (size_t)N * 4, hipMemcpyDeviceToDevice, stream);
        egnn_edge_sorted<<<(E + 255) / 256, 256, 0, stream>>>(
            node_feat, coord, edge_feat, src, dst,
            We1, be1, We2, be2, Wc1, bc1, Wc2,
            cursor, msg_sorted, E);
        aggregate_kernel<<<((size_t)N * 32 + 255) / 256, 256, 0, stream>>>(
            msg_sorted, basep, h_acc, x_acc, degv, N);
        egnn_node<<<(N + 255) / 256, 256, 0, stream>>>(
            node_feat, coord, Wn1, bn1, Wn2, bn2,
            h_acc, x_acc, degv, out_h, out_x, N);
    } else {
        // fallback: atomic path (needs only N*36+N floats)
        float* fh_acc = (float*)d_ws;
        float* fx_acc = fh_acc + (size_t)N * THID;
        float* fdeg   = fx_acc + (size_t)N * 3;
        hipMemsetAsync(d_ws, 0, sizeof(float) * (size_t)N * (THID + 3 + 1), stream);
        egnn_edge_atomic<<<(E + 255) / 256, 256, 0, stream>>>(
            node_feat, coord, edge_feat, src, dst,
            We1, be1, We2, be2, Wc1, bc1, Wc2,
            fh_acc, fx_acc, fdeg, E);
        egnn_node<<<(N + 255) / 256, 256, 0, stream>>>(
            node_feat, coord, Wn1, bn1, Wn2, bn2,
            fh_acc, fx_acc, fdeg, out_h, out_x, N);
    }
}

// Round 3
// 880.367 us; speedup vs baseline: 6.9378x; 1.1875x over previous
//
#include <hip/hip_runtime.h>
#include <math.h>

#define TIN   32
#define THID  32
#define TOUT  32
#define TEDGE 8
#define ROWU  20   // uints per sorted message row: 16 (32 bf16 h) + 3 (f32 x) + 1 pad

typedef __attribute__((ext_vector_type(8))) short bf16x8;
typedef __attribute__((ext_vector_type(4))) float f32x4;

#define MFMA16(a, b, c) __builtin_amdgcn_mfma_f32_16x16x32_bf16((a), (b), (c), 0, 0, 0)

__device__ __forceinline__ float silu_f(float x) {
    return x * (1.0f / (1.0f + __expf(-x)));
}

__device__ __forceinline__ unsigned int bf16_rne(float x) {
    unsigned int u = __float_as_uint(x);
    return (u + 0x7FFFu + ((u >> 16) & 1u)) >> 16;
}
__device__ __forceinline__ unsigned int pack2bf(float lo, float hi) {
    return bf16_rne(lo) | (bf16_rne(hi) << 16);
}

union U4F { unsigned int u[4]; bf16x8 v; };

__device__ __forceinline__ bf16x8 pack8bf(const float* f) {
    U4F t;
    t.u[0] = pack2bf(f[0], f[1]);
    t.u[1] = pack2bf(f[2], f[3]);
    t.u[2] = pack2bf(f[4], f[5]);
    t.u[3] = pack2bf(f[6], f[7]);
    return t.v;
}

// A-fragment of transposed weights: A[row=ch][k] = W[k][ch]; W is [Kreal][32] row-major.
__device__ __forceinline__ bf16x8 load_wT(const float* __restrict__ W, int kbase, int ch, int Kreal) {
    float f[8];
    #pragma unroll
    for (int e = 0; e < 8; ++e) {
        int k = kbase + e;
        f[e] = (k < Kreal) ? W[k * 32 + ch] : 0.0f;
    }
    return pack8bf(f);
}

// ---------------- phase 1: histogram of dst ----------------
__global__ __launch_bounds__(256) void hist_kernel(
    const int* __restrict__ dst, int* __restrict__ hist, int E)
{
    int e = blockIdx.x * 256 + threadIdx.x;
    if (e < E) atomicAdd(&hist[dst[e]], 1);
}

// ---------------- phase 2: exclusive scan (single block) ----------------
__global__ __launch_bounds__(1024) void scan_hist(
    const int* __restrict__ hist, int* __restrict__ base, int N)
{
    __shared__ int partial[1024];
    int t = threadIdx.x;
    int chunk = (N + 1023) / 1024;
    int begin = t * chunk;
    int end   = begin + chunk; if (end > N) end = N;
    int s = 0;
    for (int i = begin; i < end; ++i) s += hist[i];
    partial[t] = s;
    __syncthreads();
    for (int off = 1; off < 1024; off <<= 1) {
        int v = (t >= off) ? partial[t - off] : 0;
        __syncthreads();
        partial[t] += v;
        __syncthreads();
    }
    int run = (t == 0) ? 0 : partial[t - 1];
    for (int i = begin; i < end; ++i) { base[i] = run; run += hist[i]; }
    if (t == 1023) base[N] = partial[1023];
}

// ---------------- phase 3: MFMA edge MLP, write dst-sorted packed messages ----------------
// Per wave: 16-edge tile. Transposed compute D[ch][edge] = Wt x Ft using
// mfma_f32_16x16x32_bf16.  A (weights) preloaded in registers; B gathered.
// Verified layouts (16x16x32): A[row=l&15][k=(l>>4)*8+e]; B[k=(l>>4)*8+e][col=l&15];
// D[row=(l>>4)*4+q][col=l&15].
__global__ __launch_bounds__(256) void egnn_edge_mfma(
    const float* __restrict__ node_feat,
    const float* __restrict__ coord,
    const float* __restrict__ edge_feat,
    const int*   __restrict__ src,
    const int*   __restrict__ dst,
    const float* __restrict__ We1,
    const float* __restrict__ be1,
    const float* __restrict__ We2,
    const float* __restrict__ be2,
    const float* __restrict__ Wc1,
    const float* __restrict__ bc1,
    const float* __restrict__ Wc2,
    int* __restrict__ cursor,
    unsigned int* __restrict__ msg_sorted,   // [E][ROWU]
    int E)
{
    const int lane = threadIdx.x & 63;
    const int wid  = threadIdx.x >> 6;
    const int r    = lane & 15;   // edge slot within tile / col
    const int g    = lane >> 4;   // k-group

    // ---- preload weight fragments + per-lane bias/gate constants ----
    bf16x8 A1[3][2], A2[2], A3[2];
    #pragma unroll
    for (int kk = 0; kk < 3; ++kk) {
        A1[kk][0] = load_wT(We1, 32*kk + 8*g, r,      73);
        A1[kk][1] = load_wT(We1, 32*kk + 8*g, 16 + r, 73);
    }
    A2[0] = load_wT(We2, 8*g, r, 32);      A2[1] = load_wT(We2, 8*g, 16 + r, 32);
    A3[0] = load_wT(Wc1, 8*g, r, 32);      A3[1] = load_wT(Wc1, 8*g, 16 + r, 32);

    float be1v[8], be2v[8], bc1v[8], wc2v[8];
    #pragma unroll
    for (int h = 0; h < 2; ++h)
        #pragma unroll
        for (int q = 0; q < 4; ++q) {
            int ch = 16*h + 4*g + q;
            be1v[4*h+q] = be1[ch];
            be2v[4*h+q] = be2[ch];
            bc1v[4*h+q] = bc1[ch];
            wc2v[4*h+q] = Wc2[ch];
        }

    const int  ntiles = (E + 15) >> 4;
    const int  nw     = gridDim.x * 4;
    const bool Hhi    = ((g >> 1) & 1) != 0;
    const int  s0L    = 32 * (g & 1) + r;   // source lane (group 2*(g&1), slot r)
    const int  s1L    = s0L + 16;

    for (int tile = blockIdx.x * 4 + wid; tile < ntiles; tile += nw) {
        int e = tile * 16 + r;
        bool valid = (e < E);
        int ec = valid ? e : (E - 1);
        int s = src[ec], d = dst[ec];

        // ---- gather B fragments (features, bf16) ----
        float fs[8], fd[8];
        {
            const float4* sp = reinterpret_cast<const float4*>(node_feat + (size_t)s * TIN + 8*g);
            float4 u0 = sp[0], u1 = sp[1];
            fs[0]=u0.x; fs[1]=u0.y; fs[2]=u0.z; fs[3]=u0.w;
            fs[4]=u1.x; fs[5]=u1.y; fs[6]=u1.z; fs[7]=u1.w;
            const float4* dp = reinterpret_cast<const float4*>(node_feat + (size_t)d * TIN + 8*g);
            float4 w0 = dp[0], w1 = dp[1];
            fd[0]=w0.x; fd[1]=w0.y; fd[2]=w0.z; fd[3]=w0.w;
            fd[4]=w1.x; fd[5]=w1.y; fd[6]=w1.z; fd[7]=w1.w;
        }

        // geometry (computed redundantly per k-group; identical per r)
        float dx0 = coord[3*(size_t)s+0] - coord[3*(size_t)d+0];
        float dx1 = coord[3*(size_t)s+1] - coord[3*(size_t)d+1];
        float dx2 = coord[3*(size_t)s+2] - coord[3*(size_t)d+2];
        float radial = dx0*dx0 + dx1*dx1 + dx2*dx2;
        float invn = 1.0f / (sqrtf(radial) + 1e-30f);
        dx0 *= invn; dx1 *= invn; dx2 *= invn;

        float fe[8];
        #pragma unroll
        for (int i = 0; i < 8; ++i) fe[i] = 0.0f;
        if (g == 0) {
            const float4* ep = reinterpret_cast<const float4*>(edge_feat + (size_t)ec * TEDGE);
            float4 e0 = ep[0], e1 = ep[1];
            fe[0]=radial; fe[1]=e0.x; fe[2]=e0.y; fe[3]=e0.z;
            fe[4]=e0.w;   fe[5]=e1.x; fe[6]=e1.y; fe[7]=e1.z;
        } else if (g == 1) {
            fe[0] = edge_feat[(size_t)ec * TEDGE + 7];
        }

        bf16x8 Bk0 = pack8bf(fs), Bk1 = pack8bf(fd), Bk2 = pack8bf(fe);

        // ---- layer 1: a1[ch][edge] ----
        f32x4 acc0, acc1;
        #pragma unroll
        for (int q = 0; q < 4; ++q) { acc0[q] = be1v[q]; acc1[q] = be1v[4+q]; }
        acc0 = MFMA16(A1[0][0], Bk0, acc0);
        acc0 = MFMA16(A1[1][0], Bk1, acc0);
        acc0 = MFMA16(A1[2][0], Bk2, acc0);
        acc1 = MFMA16(A1[0][1], Bk0, acc1);
        acc1 = MFMA16(A1[1][1], Bk1, acc1);
        acc1 = MFMA16(A1[2][1], Bk2, acc1);

        unsigned int pk0 = pack2bf(silu_f(acc0[0]), silu_f(acc0[1]));
        unsigned int pk1 = pack2bf(silu_f(acc0[2]), silu_f(acc0[3]));
        unsigned int pk2 = pack2bf(silu_f(acc1[0]), silu_f(acc1[1]));
        unsigned int pk3 = pack2bf(silu_f(acc1[2]), silu_f(acc1[3]));

        // ---- transpose a1 (D layout) -> B2 fragment ----
        unsigned int al0 = __shfl(pk0, s0L, 64), al1 = __shfl(pk1, s0L, 64);
        unsigned int ah0 = __shfl(pk2, s0L, 64), ah1 = __shfl(pk3, s0L, 64);
        unsigned int bl0 = __shfl(pk0, s1L, 64), bl1 = __shfl(pk1, s1L, 64);
        unsigned int bh0 = __shfl(pk2, s1L, 64), bh1 = __shfl(pk3, s1L, 64);
        U4F B2u;
        B2u.u[0] = Hhi ? ah0 : al0;  B2u.u[1] = Hhi ? ah1 : al1;
        B2u.u[2] = Hhi ? bh0 : bl0;  B2u.u[3] = Hhi ? bh1 : bl1;

        // ---- layer 2: msg[ch][edge] ----
        f32x4 m0, m1;
        #pragma unroll
        for (int q = 0; q < 4; ++q) { m0[q] = be2v[q]; m1[q] = be2v[4+q]; }
        m0 = MFMA16(A2[0], B2u.v, m0);
        m1 = MFMA16(A2[1], B2u.v, m1);

        unsigned int mpk0 = pack2bf(silu_f(m0[0]), silu_f(m0[1]));
        unsigned int mpk1 = pack2bf(silu_f(m0[2]), silu_f(m0[3]));
        unsigned int mpk2 = pack2bf(silu_f(m1[0]), silu_f(m1[1]));
        unsigned int mpk3 = pack2bf(silu_f(m1[2]), silu_f(m1[3]));

        // ---- transpose msg -> B3 fragment ----
        unsigned int cl0 = __shfl(mpk0, s0L, 64), cl1 = __shfl(mpk1, s0L, 64);
        unsigned int ch0 = __shfl(mpk2, s0L, 64), ch1 = __shfl(mpk3, s0L, 64);
        unsigned int dl0 = __shfl(mpk0, s1L, 64), dl1 = __shfl(mpk1, s1L, 64);
        unsigned int dh0 = __shfl(mpk2, s1L, 64), dh1 = __shfl(mpk3, s1L, 64);
        U4F B3u;
        B3u.u[0] = Hhi ? ch0 : cl0;  B3u.u[1] = Hhi ? ch1 : cl1;
        B3u.u[2] = Hhi ? dh0 : dl0;  B3u.u[3] = Hhi ? dh1 : dl1;

        // ---- layer 3 (coord gate): c1[ch][edge] then dot with Wc2 ----
        f32x4 c0, c1;
        #pragma unroll
        for (int q = 0; q < 4; ++q) { c0[q] = bc1v[q]; c1[q] = bc1v[4+q]; }
        c0 = MFMA16(A3[0], B3u.v, c0);
        c1 = MFMA16(A3[1], B3u.v, c1);

        float gp = 0.0f;
        #pragma unroll
        for (int q = 0; q < 4; ++q) {
            gp = fmaf(silu_f(c0[q]), wc2v[q],   gp);
            gp = fmaf(silu_f(c1[q]), wc2v[4+q], gp);
        }
        gp += __shfl_xor(gp, 16, 64);
        gp += __shfl_xor(gp, 32, 64);

        // ---- scatter write (sorted row) ----
        int pos = 0;
        if (g == 0 && valid) pos = atomicAdd(&cursor[d], 1);
        pos = __shfl(pos, r, 64);
        if (valid) {
            unsigned int* base = msg_sorted + (size_t)pos * ROWU;
            uint2 lo; lo.x = mpk0; lo.y = mpk1;
            uint2 hi; hi.x = mpk2; hi.y = mpk3;
            *reinterpret_cast<uint2*>(base + 2*g)     = lo;   // dwords 2g,2g+1 (ch 4g..4g+3)
            *reinterpret_cast<uint2*>(base + 8 + 2*g) = hi;   // dwords 8+2g.. (ch 16+4g..)
            if (g == 0) {
                uint4 xv;
                xv.x = __float_as_uint(gp * dx0);
                xv.y = __float_as_uint(gp * dx1);
                xv.z = __float_as_uint(gp * dx2);
                xv.w = 0u;
                *reinterpret_cast<uint4*>(base + 16) = xv;
            }
        }
    }
}

// ---------------- phase 4: segment-sum the sorted messages ----------------
__global__ __launch_bounds__(256) void aggregate_kernel(
    const unsigned int* __restrict__ msg_sorted,
    const int* __restrict__ base,
    float* __restrict__ h_acc,   // [N][32]
    float* __restrict__ x_acc,   // [N][3]
    float* __restrict__ deg,     // [N]
    int N)
{
    int g    = (blockIdx.x * 256 + threadIdx.x) >> 5;  // node id
    int lane = threadIdx.x & 31;
    if (g >= N) return;

    int s = base[g], e = base[g+1];
    bool isH = lane < 16;
    bool isX = (lane >= 16) && (lane < 19);
    float sum0 = 0.0f, sum1 = 0.0f;
    for (int j = s; j < e; ++j) {
        unsigned int v = (lane < 19) ? msg_sorted[(size_t)j * ROWU + lane] : 0u;
        if (isH) {
            sum0 += __uint_as_float((v & 0xFFFFu) << 16);
            sum1 += __uint_as_float(v & 0xFFFF0000u);
        } else if (isX) {
            sum0 += __uint_as_float(v);
        }
    }
    if (isH) {
        float2* p = reinterpret_cast<float2*>(h_acc + (size_t)g * THID + 2 * lane);
        float2 v; v.x = sum0; v.y = sum1;
        *p = v;
    } else if (isX) {
        x_acc[(size_t)g * 3 + (lane - 16)] = sum0;
    } else if (lane == 19) {
        deg[g] = (float)(e - s);
    }
}

// ---------------- fallback: atomic edge kernel (small-ws path) ----------------
__global__ __launch_bounds__(256) void egnn_edge_atomic(
    const float* __restrict__ node_feat,
    const float* __restrict__ coord,
    const float* __restrict__ edge_feat,
    const int*   __restrict__ src,
    const int*   __restrict__ dst,
    const float* __restrict__ We1,
    const float* __restrict__ be1,
    const float* __restrict__ We2,
    const float* __restrict__ be2,
    const float* __restrict__ Wc1,
    const float* __restrict__ bc1,
    const float* __restrict__ Wc2,
    float* __restrict__ h_acc,
    float* __restrict__ x_acc,
    float* __restrict__ deg,
    int E)
{
    int e = blockIdx.x * 256 + threadIdx.x;
    if (e >= E) return;
    int s = src[e];
    int d = dst[e];
    float dx0 = coord[3*(size_t)s+0] - coord[3*(size_t)d+0];
    float dx1 = coord[3*(size_t)s+1] - coord[3*(size_t)d+1];
    float dx2 = coord[3*(size_t)s+2] - coord[3*(size_t)d+2];
    float radial = dx0*dx0 + dx1*dx1 + dx2*dx2;
    float invn = 1.0f / (sqrtf(radial) + 1e-30f);
    dx0 *= invn; dx1 *= invn; dx2 *= invn;
    float f[73];
    #pragma unroll
    for (int i = 0; i < 8; ++i) {
        f[i*4+0] = node_feat[(size_t)s*TIN + i*4+0];
        f[i*4+1] = node_feat[(size_t)s*TIN + i*4+1];
        f[i*4+2] = node_feat[(size_t)s*TIN + i*4+2];
        f[i*4+3] = node_feat[(size_t)s*TIN + i*4+3];
    }
    #pragma unroll
    for (int i = 0; i < 32; ++i) f[32+i] = node_feat[(size_t)d*TIN + i];
    f[64] = radial;
    #pragma unroll
    for (int i = 0; i < 8; ++i) f[65+i] = edge_feat[(size_t)e*TEDGE + i];
    float a1[THID];
    #pragma unroll
    for (int j = 0; j < THID; ++j) a1[j] = be1[j];
    for (int k = 0; k < 73; ++k) {
        float fk = f[k];
        #pragma unroll
        for (int j = 0; j < THID; ++j) a1[j] = fmaf(fk, We1[k*THID + j], a1[j]);
    }
    #pragma unroll
    for (int j = 0; j < THID; ++j) a1[j] = silu_f(a1[j]);
    float msg[THID];
    #pragma unroll
    for (int j = 0; j < THID; ++j) msg[j] = be2[j];
    for (int k = 0; k < THID; ++k) {
        float fk = a1[k];
        #pragma unroll
        for (int j = 0; j < THID; ++j) msg[j] = fmaf(fk, We2[k*THID + j], msg[j]);
    }
    #pragma unroll
    for (int j = 0; j < THID; ++j) msg[j] = silu_f(msg[j]);
    float c1[THID];
    #pragma unroll
    for (int j = 0; j < THID; ++j) c1[j] = bc1[j];
    for (int k = 0; k < THID; ++k) {
        float fk = msg[k];
        #pragma unroll
        for (int j = 0; j < THID; ++j) c1[j] = fmaf(fk, Wc1[k*THID + j], c1[j]);
    }
    float gate = 0.0f;
    #pragma unroll
    for (int j = 0; j < THID; ++j) gate = fmaf(silu_f(c1[j]), Wc2[j], gate);
    float* ha = h_acc + (size_t)d * THID;
    #pragma unroll
    for (int j = 0; j < THID; ++j) atomicAdd(ha + j, msg[j]);
    atomicAdd(x_acc + (size_t)d*3 + 0, gate * dx0);
    atomicAdd(x_acc + (size_t)d*3 + 1, gate * dx1);
    atomicAdd(x_acc + (size_t)d*3 + 2, gate * dx2);
    atomicAdd(deg + d, 1.0f);
}

// ---------------- phase 5: node update ----------------
__global__ __launch_bounds__(256) void egnn_node(
    const float* __restrict__ node_feat,
    const float* __restrict__ coord,
    const float* __restrict__ Wn1,
    const float* __restrict__ bn1,
    const float* __restrict__ Wn2,
    const float* __restrict__ bn2,
    const float* __restrict__ h_acc,
    const float* __restrict__ x_acc,
    const float* __restrict__ deg,
    float* __restrict__ out_h,
    float* __restrict__ out_x,
    int N)
{
    int n = blockIdx.x * 256 + threadIdx.x;
    if (n >= N) return;

    float f2[2*TIN];
    {
        const float4* p = reinterpret_cast<const float4*>(node_feat + (size_t)n * TIN);
        #pragma unroll
        for (int i = 0; i < TIN/4; ++i) {
            float4 v = p[i];
            f2[4*i+0]=v.x; f2[4*i+1]=v.y; f2[4*i+2]=v.z; f2[4*i+3]=v.w;
        }
    }
    {
        const float4* p = reinterpret_cast<const float4*>(h_acc + (size_t)n * THID);
        #pragma unroll
        for (int i = 0; i < THID/4; ++i) {
            float4 v = p[i];
            f2[TIN+4*i+0]=v.x; f2[TIN+4*i+1]=v.y; f2[TIN+4*i+2]=v.z; f2[TIN+4*i+3]=v.w;
        }
    }

    float a[THID];
    #pragma unroll
    for (int j = 0; j < THID; ++j) a[j] = bn1[j];
    #pragma unroll
    for (int k = 0; k < 2*TIN; ++k) {
        float fk = f2[k];
        #pragma unroll
        for (int j = 0; j < THID; ++j) a[j] = fmaf(fk, Wn1[k*THID + j], a[j]);
    }
    #pragma unroll
    for (int j = 0; j < THID; ++j) a[j] = silu_f(a[j]);

    float h[TOUT];
    #pragma unroll
    for (int j = 0; j < TOUT; ++j) h[j] = bn2[j];
    #pragma unroll
    for (int k = 0; k < THID; ++k) {
        float fk = a[k];
        #pragma unroll
        for (int j = 0; j < TOUT; ++j) h[j] = fmaf(fk, Wn2[k*TOUT + j], h[j]);
    }

    float4* po = reinterpret_cast<float4*>(out_h + (size_t)n * TOUT);
    #pragma unroll
    for (int i = 0; i < TOUT/4; ++i) {
        float4 v; v.x=h[4*i+0]; v.y=h[4*i+1]; v.z=h[4*i+2]; v.w=h[4*i+3];
        po[i] = v;
    }

    float dg = fmaxf(deg[n], 1.0f);
    float inv = 1.0f / dg;
    out_x[(size_t)n*3+0] = coord[(size_t)n*3+0] + x_acc[(size_t)n*3+0] * inv;
    out_x[(size_t)n*3+1] = coord[(size_t)n*3+1] + x_acc[(size_t)n*3+1] * inv;
    out_x[(size_t)n*3+2] = coord[(size_t)n*3+2] + x_acc[(size_t)n*3+2] * inv;
}

extern "C" void kernel_launch(void* const* d_in, const int* in_sizes, int n_in,
                              void* d_out, int out_size, void* d_ws, size_t ws_size,
                              hipStream_t stream) {
    const float* node_feat = (const float*)d_in[0];
    const float* coord     = (const float*)d_in[1];
    const float* edge_feat = (const float*)d_in[2];
    const int*   src       = (const int*)d_in[3];
    const int*   dst       = (const int*)d_in[4];
    const float* We1 = (const float*)d_in[5];
    const float* be1 = (const float*)d_in[6];
    const float* We2 = (const float*)d_in[7];
    const float* be2 = (const float*)d_in[8];
    const float* Wn1 = (const float*)d_in[9];
    const float* bn1 = (const float*)d_in[10];
    const float* Wn2 = (const float*)d_in[11];
    const float* bn2 = (const float*)d_in[12];
    const float* Wc1 = (const float*)d_in[13];
    const float* bc1 = (const float*)d_in[14];
    const float* Wc2 = (const float*)d_in[15];

    int N = in_sizes[0] / TIN;
    int E = in_sizes[3];

    float* out_h = (float*)d_out;
    float* out_x = out_h + (size_t)N * TOUT;

    // workspace layout (sorted path): msg_sorted first for 16B alignment
    unsigned int* msg_sorted = (unsigned int*)d_ws;
    float* h_acc = (float*)((char*)d_ws + (size_t)E * ROWU * 4);
    float* x_acc = h_acc + (size_t)N * THID;
    float* degv  = x_acc + (size_t)N * 3;
    int*   hist  = (int*)(degv + N);
    int*   basep = hist + N;
    int*   cursor = basep + (N + 1);
    size_t need = (size_t)((char*)(cursor + N) - (char*)d_ws);

    if (need <= ws_size) {
        hipMemsetAsync(hist, 0, (size_t)N * 4, stream);
        hist_kernel<<<(E + 255) / 256, 256, 0, stream>>>(dst, hist, E);
        scan_hist<<<1, 1024, 0, stream>>>(hist, basep, N);
        hipMemcpyAsync(cursor, basep, (size_t)N * 4, hipMemcpyDeviceToDevice, stream);
        egnn_edge_mfma<<<2048, 256, 0, stream>>>(
            node_feat, coord, edge_feat, src, dst,
            We1, be1, We2, be2, Wc1, bc1, Wc2,
            cursor, msg_sorted, E);
        aggregate_kernel<<<((size_t)N * 32 + 255) / 256, 256, 0, stream>>>(
            msg_sorted, basep, h_acc, x_acc, degv, N);
        egnn_node<<<(N + 255) / 256, 256, 0, stream>>>(
            node_feat, coord, Wn1, bn1, Wn2, bn2,
            h_acc, x_acc, degv, out_h, out_x, N);
    } else {
        float* fh_acc = (float*)d_ws;
        float* fx_acc = fh_acc + (size_t)N * THID;
        float* fdeg   = fx_acc + (size_t)N * 3;
        hipMemsetAsync(d_ws, 0, sizeof(float) * (size_t)N * (THID + 3 + 1), stream);
        egnn_edge_atomic<<<(E + 255) / 256, 256, 0, stream>>>(
            node_feat, coord, edge_feat, src, dst,
            We1, be1, We2, be2, Wc1, bc1, Wc2,
            fh_acc, fx_acc, fdeg, E);
        egnn_node<<<(N + 255) / 256, 256, 0, stream>>>(
            node_feat, coord, Wn1, bn1, Wn2, bn2,
            fh_acc, fx_acc, fdeg, out_h, out_x, N);
    }
}